// Round 1
// baseline (70.534 us; speedup 1.0000x reference)
//
#include <hip/hip_runtime.h>
#include <hip/hip_bf16.h>

// Conv2dLocal: B=64, C_IN=64, H=W=32, C_OUT=64, 3x3, pad 1, stride 1.
// out[b,o,h,w] = sum_{c,kh,kw} x[b,c,h+kh-1,w+kw-1] * wgt[h,w,o,c,kh,kw] + bias[o,h,w]
//
// Kernel 1 (xpose_k): x[b][c][y][xw] f32 -> xc[y][xw][b][c] bf16 (8 MB in d_ws)
// Kernel 2 (conv_k): one block per (h,w). Stage im2col patch [64][576] bf16 in LDS
//   (coalesced reads from xc, stride-9 LDS scatter), then 4 waves x mfma 16x16x32
//   over K=576 with weight streamed f32->bf16 in-register (depth-4 prefetch).

typedef __attribute__((ext_vector_type(8))) short short8;
typedef __attribute__((ext_vector_type(4))) float f32x4;

#define PSTR 584  // patch row stride (elems); 584*2=1168 B, 16B aligned for ds_read_b128

__global__ __launch_bounds__(256) void xpose_k(const float* __restrict__ x,
                                               unsigned short* __restrict__ xc) {
  // treat x as A[4096 (b*64+c)][1024 (y*32+xw)], produce xc[1024][4096], bf16 RNE
  __shared__ float tile[64][65];
  int bid = blockIdx.x;            // 64 row-tiles x 16 col-tiles
  int rt = bid >> 4, ct = bid & 15;
  int r0 = rt << 6, c0 = ct << 6;
  int lane = threadIdx.x & 63, wv = threadIdx.x >> 6;
#pragma unroll
  for (int i = 0; i < 16; ++i) {
    int r = (i << 2) + wv;
    tile[r][lane] = x[(size_t)(r0 + r) * 1024 + c0 + lane];
  }
  __syncthreads();
#pragma unroll
  for (int i = 0; i < 16; ++i) {
    int oc = (i << 2) + wv;
    unsigned int u = __float_as_uint(tile[lane][oc]);
    unsigned int r = (u + 0x7FFFu + ((u >> 16) & 1u)) >> 16;  // RNE to bf16
    xc[(size_t)(c0 + oc) * 4096 + r0 + lane] = (unsigned short)r;
  }
}

__global__ __launch_bounds__(256) void conv_k(const unsigned short* __restrict__ xc,
                                              const float* __restrict__ wgt,
                                              const float* __restrict__ bias,
                                              float* __restrict__ out) {
  __shared__ unsigned short patch[64 * PSTR];  // 74,752 B -> 2 blocks/CU

  // XCD-aware swizzle: 1024 % 8 == 0, bijective. XCD gets 4 contiguous h-rows.
  int bid = blockIdx.x;
  int sw = ((bid & 7) << 7) | (bid >> 3);
  int h = sw >> 5, w = sw & 31;
  int t = threadIdx.x;
  int hw = (h << 5) + w;

  // ---- stage im2col patch: patch[b][k], k = c*9 + tap, tap = kh*3+kw ----
  {
    int c8 = t & 7;     // c octet
    int brow = t >> 3;  // 0..31
#pragma unroll
    for (int tap = 0; tap < 9; ++tap) {
      int y = h + tap / 3 - 1;
      int xw = w + tap % 3 - 1;
      bool valid = ((unsigned)y < 32u) && ((unsigned)xw < 32u);
      const unsigned short* src = xc + ((size_t)(y * 32 + xw) << 12);
#pragma unroll
      for (int bh = 0; bh < 2; ++bh) {
        int b = brow + (bh << 5);
        uint4 v = make_uint4(0u, 0u, 0u, 0u);
        if (valid) v = *(const uint4*)(src + b * 64 + c8 * 8);  // 8 bf16, coalesced
        unsigned int uu[4] = {v.x, v.y, v.z, v.w};
        unsigned short* dst = patch + b * PSTR + tap;
        int cbase = c8 * 8;
#pragma unroll
        for (int j = 0; j < 8; ++j) {
          unsigned short e = (unsigned short)(uu[j >> 1] >> ((j & 1) * 16));
          dst[(cbase + j) * 9] = e;  // zero-padding written explicitly when !valid
        }
      }
    }
  }
  __syncthreads();

  // ---- per-wave 32x32 output tile, K=576 in 18 steps of mfma_f32_16x16x32_bf16 ----
  int wid = t >> 6, lane = t & 63;
  int wr = wid >> 1, wc = wid & 1;
  int l15 = lane & 15, l4 = lane >> 4;

  const float* wb = wgt + (size_t)hw * 36864;  // [64][576] f32, contiguous
  const float* bp0 = wb + (size_t)((wc << 5) + l15) * 576 + l4 * 8;
  const float* bp1 = bp0 + 16 * 576;
  const unsigned short* ap0 = patch + ((wr << 5) + l15) * PSTR + l4 * 8;
  const unsigned short* ap1 = ap0 + 16 * PSTR;

  f32x4 acc00 = {0.f, 0.f, 0.f, 0.f};
  f32x4 acc01 = acc00, acc10 = acc00, acc11 = acc00;

  float4 pre[4][4];  // [slot][{n0 lo, n0 hi, n1 lo, n1 hi}] — all indices static

#define LOADB(slot, step)                                  \
  do {                                                     \
    pre[slot][0] = *(const float4*)(bp0 + (step) * 32);    \
    pre[slot][1] = *(const float4*)(bp0 + (step) * 32 + 4);\
    pre[slot][2] = *(const float4*)(bp1 + (step) * 32);    \
    pre[slot][3] = *(const float4*)(bp1 + (step) * 32 + 4);\
  } while (0)

  union S8U { short8 s; unsigned int u[4]; };
  auto pack = [](const float4& lo, const float4& hi) -> short8 {
    S8U r;  // truncate f32->bf16 (weights; error budget allows)
    r.u[0] = (__float_as_uint(lo.y) & 0xFFFF0000u) | (__float_as_uint(lo.x) >> 16);
    r.u[1] = (__float_as_uint(lo.w) & 0xFFFF0000u) | (__float_as_uint(lo.z) >> 16);
    r.u[2] = (__float_as_uint(hi.y) & 0xFFFF0000u) | (__float_as_uint(hi.x) >> 16);
    r.u[3] = (__float_as_uint(hi.w) & 0xFFFF0000u) | (__float_as_uint(hi.z) >> 16);
    return r.s;
  };

#pragma unroll
  for (int s = 0; s < 4; ++s) LOADB(s, s);

#pragma unroll
  for (int s = 0; s < 18; ++s) {
    const int slot = s & 3;
    short8 a0 = *(const short8*)(ap0 + s * 32);  // ds_read_b128
    short8 a1 = *(const short8*)(ap1 + s * 32);
    short8 b0 = pack(pre[slot][0], pre[slot][1]);
    short8 b1 = pack(pre[slot][2], pre[slot][3]);
    if (s + 4 < 18) LOADB(slot, s + 4);
    acc00 = __builtin_amdgcn_mfma_f32_16x16x32_bf16(a0, b0, acc00, 0, 0, 0);
    acc01 = __builtin_amdgcn_mfma_f32_16x16x32_bf16(a0, b1, acc01, 0, 0, 0);
    acc10 = __builtin_amdgcn_mfma_f32_16x16x32_bf16(a1, b0, acc10, 0, 0, 0);
    acc11 = __builtin_amdgcn_mfma_f32_16x16x32_bf16(a1, b1, acc11, 0, 0, 0);
  }
#undef LOADB

  // ---- epilogue: C/D layout col=lane&15, row=(lane>>4)*4+reg (verified m89/m91) ----
  int o0 = (wc << 5) + l15;
  int o1 = o0 + 16;
  float bv0 = bias[o0 * 1024 + hw];
  float bv1 = bias[o1 * 1024 + hw];
  int b0r = (wr << 5) + (l4 << 2);
#pragma unroll
  for (int r = 0; r < 4; ++r) {
    int b = b0r + r;
    out[((size_t)(b * 64 + o0) << 10) + hw] = acc00[r] + bv0;
    out[((size_t)(b * 64 + o1) << 10) + hw] = acc01[r] + bv1;
    out[((size_t)((b + 16) * 64 + o0) << 10) + hw] = acc10[r] + bv0;
    out[((size_t)((b + 16) * 64 + o1) << 10) + hw] = acc11[r] + bv1;
  }
}

extern "C" void kernel_launch(void* const* d_in, const int* in_sizes, int n_in,
                              void* d_out, int out_size, void* d_ws, size_t ws_size,
                              hipStream_t stream) {
  const float* x = (const float*)d_in[0];
  const float* wgt = (const float*)d_in[1];
  const float* bias = (const float*)d_in[2];
  float* out = (float*)d_out;
  unsigned short* xc = (unsigned short*)d_ws;  // 8,388,608 B for xc[1024][4096] bf16

  hipLaunchKernelGGL(xpose_k, dim3(1024), dim3(256), 0, stream, x, xc);
  hipLaunchKernelGGL(conv_k, dim3(1024), dim3(256), 0, stream, xc, wgt, bias, out);
}

// Round 2
// 63.266 us; speedup vs baseline: 1.1149x; 1.1149x over previous
//
#include <hip/hip_runtime.h>
#include <hip/hip_bf16.h>

// Conv2dLocal: B=64, C_IN=64, H=W=32, C_OUT=64, 3x3, pad 1, stride 1.
// out[b,o,h,w] = sum_{c,kh,kw} x[b,c,h+kh-1,w+kw-1] * wgt[h,w,o,c,kh,kw] + bias[o,h,w]
//
// Kernel 1 (xpose_k): x[b][c][y][xw] f32 -> xc[y][xw][b][c] bf16 (8 MB in d_ws)
// Kernel 2 (conv_k): one block per (h,w, batch-half). M=32 rows, 37.4 KB LDS ->
//   4 blocks/CU (16 waves). Staging uses conflict-free ds_write_b128 (each thread
//   owns 72 consecutive k = 9 aligned 16B units, assembled with v_perm). MFMA loop:
//   4 waves x tile 32x16, depth-8 register prefetch of the f32 weight stream,
//   f32->bf16 pack via v_perm_b32.

typedef __attribute__((ext_vector_type(8))) short short8;
typedef __attribute__((ext_vector_type(4))) float f32x4;

#define PSTR 584  // patch row stride in bf16 elems; 1168 B = 73*16 -> rows 16B-aligned

__global__ __launch_bounds__(256) void xpose_k(const float* __restrict__ x,
                                               unsigned short* __restrict__ xc) {
  // treat x as A[4096 (b*64+c)][1024 (y*32+xw)], produce xc[1024][4096], bf16 RNE
  __shared__ float tile[64][65];
  int bid = blockIdx.x;            // 64 row-tiles x 16 col-tiles
  int rt = bid >> 4, ct = bid & 15;
  int r0 = rt << 6, c0 = ct << 6;
  int lane = threadIdx.x & 63, wv = threadIdx.x >> 6;
#pragma unroll
  for (int i = 0; i < 16; ++i) {
    int r = (i << 2) + wv;
    tile[r][lane] = x[(size_t)(r0 + r) * 1024 + c0 + lane];
  }
  __syncthreads();
#pragma unroll
  for (int i = 0; i < 16; ++i) {
    int oc = (i << 2) + wv;
    unsigned int u = __float_as_uint(tile[lane][oc]);
    unsigned int r = (u + 0x7FFFu + ((u >> 16) & 1u)) >> 16;  // RNE to bf16
    xc[(size_t)(c0 + oc) * 4096 + r0 + lane] = (unsigned short)r;
  }
}

__global__ __launch_bounds__(256, 4) void conv_k(const unsigned short* __restrict__ xc,
                                                 const float* __restrict__ wgt,
                                                 const float* __restrict__ bias,
                                                 float* __restrict__ out) {
  __shared__ unsigned short patch[32 * PSTR];  // 37,376 B -> 4 blocks/CU

  // 2048 blocks. xcd = bid&7; each XCD gets contiguous hw range [xcd*128, +128),
  // and both batch-halves (mh) of an hw land on the same XCD (weight L2-shared).
  int bid = blockIdx.x;
  int xcd = bid & 7, idx = bid >> 3;  // idx 0..255
  int hw = (xcd << 7) | (idx >> 1);
  int mh = idx & 1;
  int h = hw >> 5, w = hw & 31;
  int t = threadIdx.x;

  // ---- stage im2col half-patch: patch[b_loc][k], k = c*9 + tap ----
  {
    int c8 = t & 7;        // c octet: c = c8*8 + j
    int brow = t >> 3;     // 0..31 local batch row
    int b_glob = (mh << 5) + brow;
    uint4 v[9];
#pragma unroll
    for (int tap = 0; tap < 9; ++tap) {
      int y = h + tap / 3 - 1;
      int xw = w + tap % 3 - 1;
      bool valid = ((unsigned)y < 32u) && ((unsigned)xw < 32u);
      uint4 val = make_uint4(0u, 0u, 0u, 0u);
      if (valid)
        val = *(const uint4*)(xc + ((size_t)(y * 32 + xw) << 12) + b_glob * 64 + c8 * 8);
      v[tap] = val;  // 8 bf16 (c8*8..+7) at this tap; zeros = padding
    }
    // Thread owns k in [72*c8, 72*c8+72) for row brow: 9 aligned b128 units.
    // unit u, elem i: k_local = 8u+i -> tap = k_local%9, j = k_local/9 (all static).
    unsigned short* dst = patch + brow * PSTR + c8 * 72;
    const unsigned int* vw = (const unsigned int*)v;  // v[tap].word[q] = vw[tap*4+q]
#pragma unroll
    for (int u = 0; u < 9; ++u) {
      unsigned int wd[4];
#pragma unroll
      for (int wi = 0; wi < 4; ++wi) {
        const int kl0 = 8 * u + 2 * wi, kl1 = kl0 + 1;
        const int tapA = kl0 % 9, jA = kl0 / 9;
        const int tapB = kl1 % 9, jB = kl1 / 9;
        const unsigned int selLo = (jA & 1) ? 0x0302u : 0x0100u;   // from S1 (src b)
        const unsigned int selHi = (jB & 1) ? 0x0706u : 0x0504u;   // from S0 (src a)
        wd[wi] = __builtin_amdgcn_perm(vw[tapB * 4 + (jB >> 1)],
                                       vw[tapA * 4 + (jA >> 1)],
                                       selLo | (selHi << 16));
      }
      uint4 pk = make_uint4(wd[0], wd[1], wd[2], wd[3]);
      *(uint4*)(dst + u * 8) = pk;  // ds_write_b128, conflict-free start banks
    }
  }
  __syncthreads();

  // ---- 4 waves, each 32(M) x 16(N): 2 x mfma_f32_16x16x32_bf16 per K-step ----
  int wc = t >> 6, lane = t & 63;     // wc = o-tile 0..3
  int l15 = lane & 15, l4 = lane >> 4;

  const float* wb = wgt + (size_t)hw * 36864;                  // [64][576] f32
  const float* bp = wb + (size_t)(wc * 16 + l15) * 576 + l4 * 8;
  const unsigned short* ap0 = patch + l15 * PSTR + l4 * 8;
  const unsigned short* ap1 = ap0 + 16 * PSTR;

  f32x4 acc0 = {0.f, 0.f, 0.f, 0.f};
  f32x4 acc1 = acc0;

  float4 pre[8][2];  // depth-8 prefetch, 2 float4 (8 f32 weights) per step

#define LOADB(slot, step)                                   \
  do {                                                      \
    pre[slot][0] = *(const float4*)(bp + (step) * 32);      \
    pre[slot][1] = *(const float4*)(bp + (step) * 32 + 4);  \
  } while (0)

  union S8U { short8 s; unsigned int u[4]; };
  auto pack = [](const float4& lo, const float4& hi) -> short8 {
    S8U r;  // truncate f32->bf16: word = (hi_f32[31:16], lo_f32[31:16]) via v_perm
    r.u[0] = __builtin_amdgcn_perm(__float_as_uint(lo.y), __float_as_uint(lo.x), 0x07060302u);
    r.u[1] = __builtin_amdgcn_perm(__float_as_uint(lo.w), __float_as_uint(lo.z), 0x07060302u);
    r.u[2] = __builtin_amdgcn_perm(__float_as_uint(hi.y), __float_as_uint(hi.x), 0x07060302u);
    r.u[3] = __builtin_amdgcn_perm(__float_as_uint(hi.w), __float_as_uint(hi.z), 0x07060302u);
    return r.s;
  };

#pragma unroll
  for (int s = 0; s < 8; ++s) LOADB(s, s);

#pragma unroll
  for (int s = 0; s < 18; ++s) {
    const int slot = s & 7;
    short8 a0 = *(const short8*)(ap0 + s * 32);  // ds_read_b128
    short8 a1 = *(const short8*)(ap1 + s * 32);
    short8 b0 = pack(pre[slot][0], pre[slot][1]);
    if (s + 8 < 18) LOADB(slot, s + 8);
    acc0 = __builtin_amdgcn_mfma_f32_16x16x32_bf16(a0, b0, acc0, 0, 0, 0);
    acc1 = __builtin_amdgcn_mfma_f32_16x16x32_bf16(a1, b0, acc1, 0, 0, 0);
  }
#undef LOADB

  // ---- epilogue: C/D layout col=lane&15, row=(lane>>4)*4+reg ----
  int o = wc * 16 + l15;
  float bv = bias[o * 1024 + hw];
  int m0 = l4 << 2;
#pragma unroll
  for (int r = 0; r < 4; ++r) {
    int b = (mh << 5) + m0 + r;
    out[((size_t)(b * 64 + o) << 10) + hw] = acc0[r] + bv;
    out[((size_t)((b + 16) * 64 + o) << 10) + hw] = acc1[r] + bv;
  }
}

extern "C" void kernel_launch(void* const* d_in, const int* in_sizes, int n_in,
                              void* d_out, int out_size, void* d_ws, size_t ws_size,
                              hipStream_t stream) {
  const float* x = (const float*)d_in[0];
  const float* wgt = (const float*)d_in[1];
  const float* bias = (const float*)d_in[2];
  float* out = (float*)d_out;
  unsigned short* xc = (unsigned short*)d_ws;  // 8,388,608 B for xc[1024][4096] bf16

  hipLaunchKernelGGL(xpose_k, dim3(1024), dim3(256), 0, stream, x, xc);
  hipLaunchKernelGGL(conv_k, dim3(2048), dim3(256), 0, stream, xc, wgt, bias, out);
}

// Round 3
// 58.578 us; speedup vs baseline: 1.2041x; 1.0800x over previous
//
#include <hip/hip_runtime.h>
#include <hip/hip_bf16.h>

// Conv2dLocal: B=64, C_IN=64, H=W=32, C_OUT=64, 3x3, pad 1, stride 1.
// out[b,o,h,w] = sum_{c,kh,kw} x[b,c,h+kh-1,w+kw-1] * wgt[h,w,o,c,kh,kw] + bias[o,h,w]
//
// xpose_k: x[b][c][y][xw] f32 -> xc[y][xw][b][c] bf16 (8 MB in d_ws)
// conv_k:  block = (hw, batch-half). im2col patch [32][576->640 pad] bf16 in LDS
//   (XOR-swizzled units). Weight f32 stream via global_load_lds into a 4-slot
//   LDS ring (8 KB/step), counted vmcnt(6) pipeline, raw s_barrier x2 per step
//   (T3/T4). Weight LDS is XOR-swizzled via pre-swizzled per-lane SOURCE
//   addresses (gload_lds dest must be linear). 4 waves x (32M x 16N) MFMA.

typedef __attribute__((ext_vector_type(8))) short short8;
typedef __attribute__((ext_vector_type(4))) float f32x4;

#define PSTR 640  // patch row stride (bf16 elems) = 80 16B-units -> XOR groups fit

template <int N>
__device__ __forceinline__ void waitvm() {
  asm volatile("s_waitcnt vmcnt(%0)" ::"i"(N) : "memory");
}
__device__ __forceinline__ void waitlgkm0() {
  asm volatile("s_waitcnt lgkmcnt(0)" ::: "memory");
}
#define GLOAD16(gp, lp)                                                        \
  __builtin_amdgcn_global_load_lds(                                            \
      (const __attribute__((address_space(1))) void*)(gp),                     \
      (__attribute__((address_space(3))) void*)(lp), 16, 0, 0)

__global__ __launch_bounds__(256) void xpose_k(const float* __restrict__ x,
                                               unsigned short* __restrict__ xc) {
  __shared__ float tile[64][65];
  int bid = blockIdx.x;  // 64 row-tiles x 16 col-tiles over A[4096][1024]
  int rt = bid >> 4, ct = bid & 15;
  int r0 = rt << 6, c0 = ct << 6;
  int lane = threadIdx.x & 63, wv = threadIdx.x >> 6;
#pragma unroll
  for (int i = 0; i < 16; ++i) {
    int r = (i << 2) + wv;
    tile[r][lane] = x[(size_t)(r0 + r) * 1024 + c0 + lane];
  }
  __syncthreads();
#pragma unroll
  for (int i = 0; i < 16; ++i) {
    int oc = (i << 2) + wv;
    unsigned int u = __float_as_uint(tile[lane][oc]);
    unsigned int r = (u + 0x7FFFu + ((u >> 16) & 1u)) >> 16;  // RNE to bf16
    xc[(size_t)(c0 + oc) * 4096 + r0 + lane] = (unsigned short)r;
  }
}

__global__ __launch_bounds__(256, 2) void conv_k(const unsigned short* __restrict__ xc,
                                                 const float* __restrict__ wgt,
                                                 const float* __restrict__ bias,
                                                 float* __restrict__ out) {
  __shared__ unsigned short patch[32 * PSTR];  // 40,960 B
  __shared__ float wbuf[4][2048];              // 32,768 B ring (4 x 8 KB)

  int bid = blockIdx.x;
  int xcd = bid & 7, idx = bid >> 3;
  int hw = (xcd << 7) | (idx >> 1);  // XCD gets contiguous hw; both mh same XCD
  int mh = idx & 1;
  int h = hw >> 5, w = hw & 31;
  int t = threadIdx.x;

  const float* wb = wgt + (size_t)hw * 36864;  // [64 o][576 k] f32

  // per-thread gload_lds source/dest for the weight ring (pre-swizzled source):
  // LDS unit q4 = i*256+t holds row r=q4>>3, data-unit (q4&7)^(r&7).
  int q0 = t, q1 = 256 + t;
  int r0 = q0 >> 3, r1 = q1 >> 3;
  const float* wsA = wb + r0 * 576 + (((q0 & 7) ^ (r0 & 7)) << 2);
  const float* wsB = wb + r1 * 576 + (((q1 & 7) ^ (r1 & 7)) << 2);
  float* ldA = &wbuf[0][0] + (q0 << 2);
  float* ldB = &wbuf[0][0] + (q1 << 2);
#define ISSUE(d)                                        \
  do {                                                  \
    GLOAD16(wsA + (d) * 32, ldA + (((d) & 3) << 11));   \
    GLOAD16(wsB + (d) * 32, ldB + (((d) & 3) << 11));   \
  } while (0)

  // ---- stage im2col half-patch: patch[brow][k], k = c*9+tap, XOR-swizzled units
  {
    int c8 = t & 7;     // c octet
    int brow = t >> 3;  // 0..31
    int b_glob = (mh << 5) + brow;
    uint4 v[9];
#pragma unroll
    for (int tap = 0; tap < 9; ++tap) {
      int y = h + tap / 3 - 1;
      int xw = w + tap % 3 - 1;
      bool valid = ((unsigned)y < 32u) && ((unsigned)xw < 32u);
      uint4 val = make_uint4(0u, 0u, 0u, 0u);
      if (valid)
        val = *(const uint4*)(xc + ((size_t)(y * 32 + xw) << 12) + b_glob * 64 + c8 * 8);
      v[tap] = val;
    }
    unsigned short* dst = patch + brow * PSTR;
    int r7b = brow & 7;
    const unsigned int* vw = (const unsigned int*)v;
#pragma unroll
    for (int u = 0; u < 9; ++u) {
      unsigned int wd[4];
#pragma unroll
      for (int wi = 0; wi < 4; ++wi) {
        const int kl0 = 8 * u + 2 * wi, kl1 = kl0 + 1;
        const int tapA = kl0 % 9, jA = kl0 / 9;
        const int tapB = kl1 % 9, jB = kl1 / 9;
        const unsigned int selLo = (jA & 1) ? 0x0302u : 0x0100u;
        const unsigned int selHi = (jB & 1) ? 0x0706u : 0x0504u;
        wd[wi] = __builtin_amdgcn_perm(vw[tapB * 4 + (jB >> 1)],
                                       vw[tapA * 4 + (jA >> 1)],
                                       selLo | (selHi << 16));
      }
      int u_abs = 9 * c8 + u;
      int u_swz = (u_abs & ~7) | ((u_abs & 7) ^ r7b);
      *(uint4*)(dst + (u_swz << 3)) = make_uint4(wd[0], wd[1], wd[2], wd[3]);
    }
  }

  // prologue: fill ring slots 0..3 (issued after all staging VMEM consumption,
  // so nothing downstream drains them; they fly during the barrier below)
  ISSUE(0); ISSUE(1); ISSUE(2); ISSUE(3);

  waitlgkm0();                           // own ds_writes of patch complete
  __builtin_amdgcn_sched_barrier(0);
  __builtin_amdgcn_s_barrier();          // patch visible to all; ring in flight

  // ---- 4 waves x (32M x 16N), K=576 in 18 steps ----
  int wc = t >> 6, lane = t & 63;
  int l15 = lane & 15, l4 = lane >> 4;
  int l7 = l15 & 7;

  // A reads (bf16, swizzled): elem group (s>>1), unit low3 = (4*(s&1)+l4)^l7
  const unsigned short* apE = patch + l15 * PSTR + ((l4 ^ l7) << 3);
  const unsigned short* apO = patch + l15 * PSTR + (((4 + l4) ^ l7) << 3);
  // W reads (f32, swizzled): row R = wc*16+l15, units (2*l4)^r7 / (2*l4+1)^r7
  int R = wc * 16 + l15;
  int r7 = R & 7;
  int offLo = R * 32 + (((2 * l4) ^ r7) << 2);
  int offHi = R * 32 + (((2 * l4 + 1) ^ r7) << 2);

  f32x4 acc0 = {0.f, 0.f, 0.f, 0.f};
  f32x4 acc1 = acc0;

  union S8U { short8 s; unsigned int u[4]; };
  auto pack = [](const float4& lo, const float4& hi) -> short8 {
    S8U r;  // truncate f32->bf16 via v_perm
    r.u[0] = __builtin_amdgcn_perm(__float_as_uint(lo.y), __float_as_uint(lo.x), 0x07060302u);
    r.u[1] = __builtin_amdgcn_perm(__float_as_uint(lo.w), __float_as_uint(lo.z), 0x07060302u);
    r.u[2] = __builtin_amdgcn_perm(__float_as_uint(hi.y), __float_as_uint(hi.x), 0x07060302u);
    r.u[3] = __builtin_amdgcn_perm(__float_as_uint(hi.w), __float_as_uint(hi.z), 0x07060302u);
    return r.s;
  };

#pragma unroll
  for (int s = 0; s < 18; ++s) {
    // wait slot s ready: steady-state outstanding 8, oldest 2 are step-s's
    constexpr_wait: ;
    if      (s <= 14) waitvm<6>();
    else if (s == 15) waitvm<4>();
    else if (s == 16) waitvm<2>();
    else              waitvm<0>();
    __builtin_amdgcn_s_barrier();        // all waves' slot-s loads complete

    const unsigned short* ab = ((s & 1) ? apO : apE) + (s >> 1) * 64;
    short8 a0 = *(const short8*)ab;                    // ds_read_b128
    short8 a1 = *(const short8*)(ab + 16 * PSTR);
    const float* wp = &wbuf[0][0] + ((s & 3) << 11);
    float4 wlo = *(const float4*)(wp + offLo);
    float4 whi = *(const float4*)(wp + offHi);

    waitlgkm0();                         // my reads of slot s&3 done
    __builtin_amdgcn_sched_barrier(0);   // (rule #18) nothing crosses
    __builtin_amdgcn_s_barrier();        // everyone's reads done -> safe to reuse

    if (s + 4 < 18) ISSUE(s + 4);        // refill slot (s+4)&3 == s&3

    short8 b0 = pack(wlo, whi);
    acc0 = __builtin_amdgcn_mfma_f32_16x16x32_bf16(a0, b0, acc0, 0, 0, 0);
    acc1 = __builtin_amdgcn_mfma_f32_16x16x32_bf16(a1, b0, acc1, 0, 0, 0);
  }
#undef ISSUE

  // ---- epilogue: C/D layout col=lane&15, row=(lane>>4)*4+reg ----
  int o = wc * 16 + l15;
  float bv = bias[o * 1024 + hw];
  int m0 = l4 << 2;
#pragma unroll
  for (int r = 0; r < 4; ++r) {
    int b = (mh << 5) + m0 + r;
    out[((size_t)(b * 64 + o) << 10) + hw] = acc0[r] + bv;
    out[((size_t)((b + 16) * 64 + o) << 10) + hw] = acc1[r] + bv;
  }
}

extern "C" void kernel_launch(void* const* d_in, const int* in_sizes, int n_in,
                              void* d_out, int out_size, void* d_ws, size_t ws_size,
                              hipStream_t stream) {
  const float* x = (const float*)d_in[0];
  const float* wgt = (const float*)d_in[1];
  const float* bias = (const float*)d_in[2];
  float* out = (float*)d_out;
  unsigned short* xc = (unsigned short*)d_ws;  // 8 MB

  hipLaunchKernelGGL(xpose_k, dim3(1024), dim3(256), 0, stream, x, xc);
  hipLaunchKernelGGL(conv_k, dim3(2048), dim3(256), 0, stream, xc, wgt, bias, out);
}